// Round 7
// baseline (1378.680 us; speedup 1.0000x reference)
//
#include <hip/hip_runtime.h>

namespace {

constexpr int D  = 64;    // channels per head
constexpr int T  = 2048;  // sequence length
constexpr int NT = T / 64;
constexpr float SCL = 0.125f * 1.44269504088896340736f;  // scale^2 * log2(e)

// workspace layout (units: unsigned short):
//  [0, 64*32*8192)             KV tiles: (h*32+kt)*8192
//     K: first 4096 shorts, [s][c] rows of 64, granule-swizzled (16-row quarter = contiguous 2 KB)
//     V: next 4096 shorts, QUARTER-BLOCKED: quarter q (2 KB) = rows c of 16 s, granules of 4 shorts swizzled g^((c>>2)&3)
//  [QP_OFF, ...)               Q tiles: (h*32+qt64)*4096 swizzled [t][c], PRE-SCALED by SCL
constexpr size_t QP_OFF  = (size_t)64 * 32 * 8192;
constexpr size_t WS_NEED = ((size_t)64 * 32 * 8192 + (size_t)64 * 32 * 4096) * 2;  // 50331648 B

typedef __bf16 bf16x8 __attribute__((ext_vector_type(8)));
typedef float  f32x4  __attribute__((ext_vector_type(4)));
typedef unsigned short u16x4 __attribute__((ext_vector_type(4)));
typedef unsigned short u16x8 __attribute__((ext_vector_type(8)));
typedef unsigned int   u32x2 __attribute__((ext_vector_type(2)));
typedef short          s16x4 __attribute__((ext_vector_type(4)));

__device__ inline unsigned short f2bf(float f) {   // RNE fp32->bf16, finite inputs
    unsigned int u = __builtin_bit_cast(unsigned int, f);
    u += 0x7FFFu + ((u >> 16) & 1u);
    return (unsigned short)(u >> 16);
}

__device__ inline unsigned int pkbf(float a, float b) {
#if __has_builtin(__builtin_amdgcn_cvt_pk_bf16_f32)
    auto r = __builtin_amdgcn_cvt_pk_bf16_f32(a, b);
    static_assert(sizeof(r) == 4, "cvt_pk_bf16 size");
    return __builtin_bit_cast(unsigned int, r);
#else
    return (unsigned int)f2bf(a) | ((unsigned int)f2bf(b) << 16);
#endif
}

// 64-short rows, 16B granules XOR-swizzled by ((row>>1)&7) (K/Q images).
__device__ inline int frag_off(int row, int c0) {
    int g = (c0 >> 3) ^ ((row >> 1) & 7);
    return row * 64 + g * 8;
}

__device__ inline void async_cp16(const void* g, void* l) {
    __builtin_amdgcn_global_load_lds(
        (const __attribute__((address_space(1))) unsigned int*)g,
        (__attribute__((address_space(3))) unsigned int*)l, 16, 0, 0);
}

// ---------------- pre-pass: fp32 -> bf16, swizzled tiles (exact R0) ----------
__global__ __launch_bounds__(256)
void prepass(const float* __restrict__ qkv, unsigned short* __restrict__ ws) {
    const int tile = blockIdx.x, h = blockIdx.y, z = blockIdx.z;
    const int tid = threadIdx.x;
    const float* src = qkv + (size_t)h * 3 * D * T + (size_t)z * D * T + tile * 64;
    __shared__ unsigned short L[4096];

    if (z == 2) {  // V: quarter-blocked [wq][c][16s], granule(4sh) swizzle g^((c>>2)&3)
        unsigned short* dst = ws + (size_t)(h * 32 + tile) * 8192 + 4096;
        const int c = tid >> 2, g = tid & 3;
        const int sg = g ^ ((c >> 2) & 3);           // source granule (s-local/4)
        #pragma unroll
        for (int wq = 0; wq < 4; wq++) {
            f32x4 a = *(const f32x4*)(src + (size_t)c * T + wq * 16 + sg * 4);
            u16x4 wv = { f2bf(a[0]), f2bf(a[1]), f2bf(a[2]), f2bf(a[3]) };
            *(u16x4*)(dst + wq * 1024 + tid * 4) = wv;   // coalesced 8B stores
        }
    } else {       // Q/K: transpose [c][t] -> swizzled [t][c] via LDS
        const float m = (z == 0) ? SCL : 1.0f;   // fold softmax scale into Q
        const int c0 = (tid >> 4) * 4, s4 = tid & 15;
        float fr[4][4];
        #pragma unroll
        for (int r = 0; r < 4; r++)
            *(f32x4*)fr[r] = *(const f32x4*)(src + (size_t)(c0 + r) * T + s4 * 4);
        #pragma unroll
        for (int j = 0; j < 4; j++) {
            int trow = s4 * 4 + j;
            u16x4 wv = { f2bf(fr[0][j] * m), f2bf(fr[1][j] * m),
                         f2bf(fr[2][j] * m), f2bf(fr[3][j] * m) };
            *(u16x4*)(L + frag_off(trow, c0) + (c0 & 7)) = wv;
        }
        __syncthreads();
        unsigned short* dst = (z == 0)
            ? ws + QP_OFF + (size_t)(h * 32 + tile) * 4096
            : ws + (size_t)(h * 32 + tile) * 8192;
        #pragma unroll
        for (int i = 0; i < 2; i++)
            *(u16x8*)(dst + tid * 16 + i * 8) = *(const u16x8*)(L + tid * 16 + i * 8);
    }
}

// ---------------- main: 8-wave c x t split flash attention -------------------
// Block = 512 threads = 8 waves; wave w = (ch = w>>2, ts = w&3).
// Wave owns t-rows {16ts..16ts+16} in BOTH 64-t halves (2 strips) and ONLY
// the c-half [32ch, 32ch+32) of the output. QK^T + softmax are computed
// FULLY per wave (P redundant x2 across the ch pair -- MFMA/trans pipes are
// <15% busy, redundancy is cheap); PV + acc halve. Register demand is
// provably small: acc_o[2][2]=16 + bQ[2][2]=16 + ~30 transient < 64 cap
// (R6's s-split needed ~95-120 under an 85 cap -> spilled; tripwire fired).
// __launch_bounds__(512,8): 64-reg cap -> 4 blocks x 8 waves = 32 waves/CU
// potential (2x R5), LDS 4x32KB=128KB fits, grid 1024 = exactly 4/CU.
// NO merge epilogue: c x t outputs disjoint; every wave owns a full l.
// Staging skeleton byte-identical to proven R4/R5: shared 16KB tile dbuf,
// raw s_barrier pair, stage distance 2, 2 cps/thread -> vmcnt(2) steady.

#define STAGE(J, B)                                                          \
  { const char* g = kvb + (size_t)(J) * 16384;                               \
    char* lk = lbase + (B) * 16384;                                          \
    async_cp16(g,        lk);                                                \
    async_cp16(g + 8192, lk + 8192); }

#define BODY(KT, B, DO_STAGE, WAITIMM)                                       \
  {                                                                          \
    __builtin_amdgcn_s_waitcnt(WAITIMM);  /* own tile-KT cps landed */       \
    __builtin_amdgcn_s_barrier();         /* ALL waves' tile-KT landed */    \
    __builtin_amdgcn_sched_barrier(0);    /* no ds_read hoists above */      \
    _Pragma("unroll")                                                        \
    for (int qq = 0; qq < 4; qq++) {      /* all 4 s-quarters (full softmax) */\
      const char* kb = sbuf + (B) * 16384 + qq * 2048;                       \
      const char* vb = kb + 8192;                                            \
      bf16x8 aK0 = *(const bf16x8*)(kb + aK0o);                              \
      bf16x8 aK1 = *(const bf16x8*)(kb + aK1o);                              \
      s16x4 aV0 = *(const s16x4*)(vb + aVoc);        /* this ch only */      \
      s16x4 aV1 = *(const s16x4*)(vb + aVoc + 512);                          \
      _Pragma("unroll")                                                      \
      for (int st = 0; st < 2; st++) {                                       \
        f32x4 s = __builtin_amdgcn_mfma_f32_16x16x32_bf16(                   \
            aK0, bQ[st][0], ZF, 0, 0, 0);                                    \
        s = __builtin_amdgcn_mfma_f32_16x16x32_bf16(aK1, bQ[st][1], s, 0,0,0);\
        float p0 = __builtin_amdgcn_exp2f(s[0]);                             \
        float p1 = __builtin_amdgcn_exp2f(s[1]);                             \
        float p2 = __builtin_amdgcn_exp2f(s[2]);                             \
        float p3 = __builtin_amdgcn_exp2f(s[3]);                             \
        l_acc[st] += (p0 + p1) + (p2 + p3);                                  \
        u32x2 pk = { pkbf(p0, p1), pkbf(p2, p3) };                           \
        s16x4 bP = __builtin_bit_cast(s16x4, pk);                            \
        acc_o[st][0] = __builtin_amdgcn_mfma_f32_16x16x16bf16_1k(            \
            aV0, bP, acc_o[st][0], 0, 0, 0);                                 \
        acc_o[st][1] = __builtin_amdgcn_mfma_f32_16x16x16bf16_1k(            \
            aV1, bP, acc_o[st][1], 0, 0, 0);                                 \
      }                                                                      \
      __builtin_amdgcn_sched_barrier(0);  /* bound liveness per quarter */   \
    }                                                                        \
    if (DO_STAGE) {                                                          \
      __builtin_amdgcn_s_waitcnt(0xC07F);  /* lgkmcnt(0): reads done */      \
      __builtin_amdgcn_s_barrier();        /* buf (B) free to overwrite */   \
      STAGE((KT) + 2, B)                                                     \
    }                                                                        \
  }

__global__ __launch_bounds__(512, 8)
void attn_main(const unsigned short* __restrict__ ws, float* __restrict__ out) {
    const int h  = blockIdx.x;      // head pinned to XCD h%8 for L2 locality
    const int qt = blockIdx.y;      // 128-t Q-block
    const int t0 = qt * 128;
    const int tid  = threadIdx.x;
    const int lane = tid & 63;
    const int w    = tid >> 6;
    const int ch   = w >> 2;        // c-half of the output: [32ch, 32ch+32)
    const int ts   = w & 3;         // t-strip: rows 16ts..16ts+16 of each half
    const int ln   = lane & 15, q4 = lane >> 4;

    __shared__ char sbuf[32768];    // 2 x 16KB shared KV staging (dbuf)
    char* lbase = sbuf + tid * 16;  // staging: thread copies [tid*16] and [8192+tid*16]

    // per-lane fragment byte offsets (quarter-local)
    const int aK0o = 2 * frag_off(ln, q4 * 8);
    const int aK1o = 2 * frag_off(ln, 32 + q4 * 8);
    const int aVoc = 32 * ln + 2 * ((q4 ^ ((ln >> 2) & 3)) * 4) + ch * 1024;

    // Q fragments: rows 16ts+ln of each 64-t half (two strips, 4 x 16B loads)
    const unsigned short* qtile = ws + QP_OFF + (size_t)(h * 32 + qt * 2) * 4096;
    bf16x8 bQ[2][2];
    #pragma unroll
    for (int st = 0; st < 2; st++) {
        bQ[st][0] = *(const bf16x8*)(qtile + st * 4096 + frag_off(16 * ts + ln, q4 * 8));
        bQ[st][1] = *(const bf16x8*)(qtile + st * 4096 + frag_off(16 * ts + ln, 32 + q4 * 8));
    }

    const char* kvb = (const char*)ws + (size_t)(h * 32) * 16384 + tid * 16;
    STAGE(0, 0)                      // tiles 0,1 in flight (2 cps/thread each)
    STAGE(1, 1)

    const f32x4 ZF = {0.f, 0.f, 0.f, 0.f};
    f32x4 acc_o[2][2];   // [strip][ci']: O rows c=32ch+16ci'+q4*4+rr, col t=ln
    #pragma unroll
    for (int st = 0; st < 2; st++)
        #pragma unroll
        for (int ci = 0; ci < 2; ci++) acc_o[st][ci] = ZF;
    float l_acc[2] = {0.f, 0.f};

    #pragma unroll 1
    for (int m = 0; m < 15; m++) {   // kt = 0..29
        BODY(2 * m,     0, 1, 0x0F72)   // vmcnt(2): tile KT landed
        BODY(2 * m + 1, 1, 1, 0x0F72)
    }
    BODY(30, 0, 0, 0x0F72)           // no stage; tile 31 still in flight
    BODY(31, 1, 0, 0x0F70)           // vmcnt(0)

    // ---- epilogue: l over q4 groups, direct store (no LDS, no merge) ----
    #pragma unroll
    for (int st = 0; st < 2; st++) {
        float sl = l_acc[st];
        sl += __shfl_xor(sl, 16, 64);
        sl += __shfl_xor(sl, 32, 64);
        const float linv = 1.0f / sl;
        float* ob = out + (size_t)h * D * T + t0 + st * 64 + 16 * ts + ln;
        #pragma unroll
        for (int ci = 0; ci < 2; ci++)
            #pragma unroll
            for (int rr = 0; rr < 4; rr++)
                ob[(size_t)(32 * ch + 16 * ci + q4 * 4 + rr) * T] = acc_o[st][ci][rr] * linv;
    }
}

// ---------------- fallback (proven): used if ws too small --------------------
__device__ inline bf16x8 frag8(const unsigned short* p, int row, int c0) {
    return *(const bf16x8*)(p + frag_off(row, c0));
}

__global__ __launch_bounds__(256)
void attn_fallback(const float* __restrict__ qkv, float* __restrict__ out) {
    const int h     = blockIdx.y;
    const int t0    = blockIdx.x * 64;
    const int tid   = threadIdx.x;
    const int lane  = tid & 63;
    const int strip = tid >> 6;
    const int ln    = lane & 15;
    const int q4    = lane >> 4;

    __shared__ unsigned short Qs[64 * D];
    __shared__ unsigned short Ks[64 * D];
    __shared__ unsigned short Vs[D * 64];
    __shared__ unsigned short Pss[64 * 64];
    __shared__ float l_lds[64];

    const float* qb = qkv + (size_t)h * 3 * D * T;
    const float* kb = qb + (size_t)D * T;
    const float* vb = qb + (size_t)(2 * D) * T;
    const int s4 = tid & 15;
    const int c0 = (tid >> 4) * 4;
    {
        float fr[4][4];
        #pragma unroll
        for (int r = 0; r < 4; r++)
            *(f32x4*)fr[r] = *(const f32x4*)(qb + (size_t)(c0 + r) * T + t0 + s4 * 4);
        #pragma unroll
        for (int j = 0; j < 4; j++) {
            int trow = s4 * 4 + j;
            u16x4 wv = { f2bf(fr[0][j]), f2bf(fr[1][j]), f2bf(fr[2][j]), f2bf(fr[3][j]) };
            *(u16x4*)(Qs + frag_off(trow, c0) + (c0 & 7)) = wv;
        }
    }
    __syncthreads();
    const int arow = strip * 16 + ln;
    const int kg   = q4 * 8;
    const bf16x8 aq0 = frag8(Qs, arow, kg);
    const bf16x8 aq1 = frag8(Qs, arow, 32 + kg);
    f32x4 acc_o[4];
    #pragma unroll
    for (int m = 0; m < 4; m++) acc_o[m] = (f32x4){0.f, 0.f, 0.f, 0.f};
    float l_acc[4] = {0.f, 0.f, 0.f, 0.f};
    constexpr float S2 = 0.125f * 1.44269504088896340736f;
    for (int kt = 0; kt < NT; kt++) {
        const int s0 = kt * 64;
        float kr[4][4], vr[4][4];
        #pragma unroll
        for (int r = 0; r < 4; r++)
            *(f32x4*)kr[r] = *(const f32x4*)(kb + (size_t)(c0 + r) * T + s0 + s4 * 4);
        #pragma unroll
        for (int r = 0; r < 4; r++)
            *(f32x4*)vr[r] = *(const f32x4*)(vb + (size_t)(c0 + r) * T + s0 + s4 * 4);
        __syncthreads();
        #pragma unroll
        for (int j = 0; j < 4; j++) {
            int srow = s4 * 4 + j;
            u16x4 wk = { f2bf(kr[0][j]), f2bf(kr[1][j]), f2bf(kr[2][j]), f2bf(kr[3][j]) };
            *(u16x4*)(Ks + frag_off(srow, c0) + (c0 & 7)) = wk;
        }
        #pragma unroll
        for (int r = 0; r < 4; r++) {
            int row = c0 + r, cc = s4 * 4;
            u16x4 wv = { f2bf(vr[r][0]), f2bf(vr[r][1]), f2bf(vr[r][2]), f2bf(vr[r][3]) };
            *(u16x4*)(Vs + frag_off(row, cc) + (cc & 7)) = wv;
        }
        __syncthreads();
        f32x4 accs[4];
        #pragma unroll
        for (int ns = 0; ns < 4; ns++) {
            bf16x8 b0 = frag8(Ks, ns * 16 + ln, kg);
            bf16x8 b1 = frag8(Ks, ns * 16 + ln, 32 + kg);
            f32x4 z = {0.f, 0.f, 0.f, 0.f};
            z = __builtin_amdgcn_mfma_f32_16x16x32_bf16(aq0, b0, z, 0, 0, 0);
            z = __builtin_amdgcn_mfma_f32_16x16x32_bf16(aq1, b1, z, 0, 0, 0);
            accs[ns] = z;
        }
        #pragma unroll
        for (int ns = 0; ns < 4; ns++) {
            int scol = ns * 16 + ln;
            #pragma unroll
            for (int r = 0; r < 4; r++) {
                float p = __builtin_amdgcn_exp2f(accs[ns][r] * S2);
                l_acc[r] += p;
                int trow = strip * 16 + q4 * 4 + r;
                int g = ((scol >> 3) ^ ((trow >> 1) & 7));
                Pss[trow * 64 + g * 8 + (scol & 7)] = f2bf(p);
            }
        }
        bf16x8 bp0 = frag8(Pss, arow, kg);
        bf16x8 bp1 = frag8(Pss, arow, 32 + kg);
        #pragma unroll
        for (int ms = 0; ms < 4; ms++) {
            bf16x8 av0 = frag8(Vs, ms * 16 + ln, kg);
            bf16x8 av1 = frag8(Vs, ms * 16 + ln, 32 + kg);
            acc_o[ms] = __builtin_amdgcn_mfma_f32_16x16x32_bf16(av0, bp0, acc_o[ms], 0, 0, 0);
            acc_o[ms] = __builtin_amdgcn_mfma_f32_16x16x32_bf16(av1, bp1, acc_o[ms], 0, 0, 0);
        }
    }
    #pragma unroll
    for (int r = 0; r < 4; r++) {
        float s = l_acc[r];
        s += __shfl_xor(s, 1, 64);
        s += __shfl_xor(s, 2, 64);
        s += __shfl_xor(s, 4, 64);
        s += __shfl_xor(s, 8, 64);
        if (ln == 0) l_lds[strip * 16 + q4 * 4 + r] = s;
    }
    const float linv = 1.0f / l_lds[strip * 16 + ln];
    const int tg = t0 + strip * 16 + ln;
    float* ob = out + (size_t)h * D * T;
    #pragma unroll
    for (int ms = 0; ms < 4; ms++)
        #pragma unroll
        for (int r = 0; r < 4; r++) {
            int c = ms * 16 + q4 * 4 + r;
            ob[(size_t)c * T + tg] = acc_o[ms][r] * linv;
        }
}

} // namespace

extern "C" void kernel_launch(void* const* d_in, const int* in_sizes, int n_in,
                              void* d_out, int out_size, void* d_ws, size_t ws_size,
                              hipStream_t stream) {
    const float* qkv = (const float*)d_in[0];
    float* out = (float*)d_out;
    if (ws_size >= WS_NEED) {
        prepass<<<dim3(32, 64, 3), 256, 0, stream>>>(qkv, (unsigned short*)d_ws);
        attn_main<<<dim3(64, 16), 512, 0, stream>>>((const unsigned short*)d_ws, out);
    } else {
        attn_fallback<<<dim3(32, 64), 256, 0, stream>>>(qkv, out);
    }
}

// Round 8
// 251.927 us; speedup vs baseline: 5.4725x; 5.4725x over previous
//
#include <hip/hip_runtime.h>

namespace {

constexpr int D  = 64;    // channels per head
constexpr int T  = 2048;  // sequence length
constexpr int NT = T / 64;
constexpr float SCL = 0.125f * 1.44269504088896340736f;  // scale^2 * log2(e)

// workspace layout (units: unsigned short):
//  [0, 64*32*8192)             KV tiles: (h*32+kt)*8192
//     K: first 4096 shorts, [s][c] rows of 64, granule-swizzled (16-row quarter = contiguous 2 KB)
//     V: next 4096 shorts, QUARTER-BLOCKED: quarter q (2 KB) = rows c of 16 s, granules of 4 shorts swizzled g^((c>>2)&3)
//  [QP_OFF, ...)               Q tiles: (h*32+qt64)*4096 swizzled [t][c], PRE-SCALED by SCL
constexpr size_t QP_OFF  = (size_t)64 * 32 * 8192;
constexpr size_t WS_NEED = ((size_t)64 * 32 * 8192 + (size_t)64 * 32 * 4096) * 2;  // 50331648 B

typedef __bf16 bf16x8 __attribute__((ext_vector_type(8)));
typedef float  f32x4  __attribute__((ext_vector_type(4)));
typedef unsigned short u16x4 __attribute__((ext_vector_type(4)));
typedef unsigned short u16x8 __attribute__((ext_vector_type(8)));
typedef unsigned int   u32x2 __attribute__((ext_vector_type(2)));
typedef short          s16x4 __attribute__((ext_vector_type(4)));

__device__ inline unsigned short f2bf(float f) {   // RNE fp32->bf16, finite inputs
    unsigned int u = __builtin_bit_cast(unsigned int, f);
    u += 0x7FFFu + ((u >> 16) & 1u);
    return (unsigned short)(u >> 16);
}

__device__ inline unsigned int pkbf(float a, float b) {
#if __has_builtin(__builtin_amdgcn_cvt_pk_bf16_f32)
    auto r = __builtin_amdgcn_cvt_pk_bf16_f32(a, b);
    static_assert(sizeof(r) == 4, "cvt_pk_bf16 size");
    return __builtin_bit_cast(unsigned int, r);
#else
    return (unsigned int)f2bf(a) | ((unsigned int)f2bf(b) << 16);
#endif
}

// 64-short rows, 16B granules XOR-swizzled by ((row>>1)&7) (K/Q images).
__device__ inline int frag_off(int row, int c0) {
    int g = (c0 >> 3) ^ ((row >> 1) & 7);
    return row * 64 + g * 8;
}

__device__ inline void async_cp16(const void* g, void* l) {
    __builtin_amdgcn_global_load_lds(
        (const __attribute__((address_space(1))) unsigned int*)g,
        (__attribute__((address_space(3))) unsigned int*)l, 16, 0, 0);
}

// ---------------- pre-pass: fp32 -> bf16, swizzled tiles (exact R0) ----------
__global__ __launch_bounds__(256)
void prepass(const float* __restrict__ qkv, unsigned short* __restrict__ ws) {
    const int tile = blockIdx.x, h = blockIdx.y, z = blockIdx.z;
    const int tid = threadIdx.x;
    const float* src = qkv + (size_t)h * 3 * D * T + (size_t)z * D * T + tile * 64;
    __shared__ unsigned short L[4096];

    if (z == 2) {  // V: quarter-blocked [wq][c][16s], granule(4sh) swizzle g^((c>>2)&3)
        unsigned short* dst = ws + (size_t)(h * 32 + tile) * 8192 + 4096;
        const int c = tid >> 2, g = tid & 3;
        const int sg = g ^ ((c >> 2) & 3);           // source granule (s-local/4)
        #pragma unroll
        for (int wq = 0; wq < 4; wq++) {
            f32x4 a = *(const f32x4*)(src + (size_t)c * T + wq * 16 + sg * 4);
            u16x4 wv = { f2bf(a[0]), f2bf(a[1]), f2bf(a[2]), f2bf(a[3]) };
            *(u16x4*)(dst + wq * 1024 + tid * 4) = wv;   // coalesced 8B stores
        }
    } else {       // Q/K: transpose [c][t] -> swizzled [t][c] via LDS
        const float m = (z == 0) ? SCL : 1.0f;   // fold softmax scale into Q
        const int c0 = (tid >> 4) * 4, s4 = tid & 15;
        float fr[4][4];
        #pragma unroll
        for (int r = 0; r < 4; r++)
            *(f32x4*)fr[r] = *(const f32x4*)(src + (size_t)(c0 + r) * T + s4 * 4);
        #pragma unroll
        for (int j = 0; j < 4; j++) {
            int trow = s4 * 4 + j;
            u16x4 wv = { f2bf(fr[0][j] * m), f2bf(fr[1][j] * m),
                         f2bf(fr[2][j] * m), f2bf(fr[3][j] * m) };
            *(u16x4*)(L + frag_off(trow, c0) + (c0 & 7)) = wv;
        }
        __syncthreads();
        unsigned short* dst = (z == 0)
            ? ws + QP_OFF + (size_t)(h * 32 + tile) * 4096
            : ws + (size_t)(h * 32 + tile) * 8192;
        #pragma unroll
        for (int i = 0; i < 2; i++)
            *(u16x8*)(dst + tid * 16 + i * 8) = *(const u16x8*)(L + tid * 16 + i * 8);
    }
}

// ---------------- main: t-split TQ=128 flash attention, TRI-buffer -----------
// R5 body (proven best: 104.2 us) with two evidence-backed deltas:
//  (1) TRIPLE-buffered shared staging (3 x 16KB) -> ONE barrier per body and
//      no per-body lgkmcnt(0) drain. Safety: barrier-at-body-top bounds wave
//      drift to <1 body; a wave's MFMA consumption implies its ds_reads of
//      buf (KT+2)%3 (last read at body KT-1) completed, so staging that buf
//      right after barrier KT is WAR-safe for all waves.
//  (2) STAGE issued EARLY (right after the barrier, before compute): HBM/L2
//      latency hides under this body's MFMA+exp (T14 issue-early).
//  (3) s_setprio(1) around the compute cluster (guide T5: attn +4-7%).
// vmcnt cadence unchanged: 4 cps/STAGE, distance 2 -> steady vmcnt(4).

#define STAGE(J, SB)                                                         \
  { const char* g = kvb + (size_t)(J) * 16384;                               \
    char* lk = lbase + (SB) * 16384;                                         \
    async_cp16(g,         lk);                                               \
    async_cp16(g + 4096,  lk + 4096);                                        \
    async_cp16(g + 8192,  lk + 8192);                                        \
    async_cp16(g + 12288, lk + 12288); }

#define BODY(KT, B, SB, DO_STAGE, WAITIMM)                                   \
  {                                                                          \
    __builtin_amdgcn_s_waitcnt(WAITIMM);  /* own tile-KT cps landed */       \
    __builtin_amdgcn_s_barrier();         /* ALL waves' tile-KT landed;      \
                                             also: everyone done reading     \
                                             buf SB (body KT-1) */           \
    __builtin_amdgcn_sched_barrier(0);    /* no ds_read hoists above */      \
    if (DO_STAGE) STAGE((KT) + 2, SB)     /* issue-early: hides under MFMA */\
    __builtin_amdgcn_s_setprio(1);                                           \
    _Pragma("unroll")                                                        \
    for (int qq = 0; qq < 4; qq++) {                                         \
      const char* kb = sbuf + (B) * 16384 + qq * 2048;                       \
      const char* vb = sbuf + (B) * 16384 + 8192 + qq * 2048;                \
      bf16x8 aK0 = *(const bf16x8*)(kb + aK0o);                              \
      bf16x8 aK1 = *(const bf16x8*)(kb + aK1o);                              \
      s16x4 aV0 = *(const s16x4*)(vb + aVo);                                 \
      s16x4 aV1 = *(const s16x4*)(vb + aVo + 512);                           \
      s16x4 aV2 = *(const s16x4*)(vb + aVo + 1024);                          \
      s16x4 aV3 = *(const s16x4*)(vb + aVo + 1536);                          \
      _Pragma("unroll")                                                      \
      for (int st = 0; st < 2; st++) {                                       \
        f32x4 s = __builtin_amdgcn_mfma_f32_16x16x32_bf16(                   \
            aK0, bQ[st][0], ZF, 0, 0, 0);                                    \
        s = __builtin_amdgcn_mfma_f32_16x16x32_bf16(aK1, bQ[st][1], s, 0,0,0);\
        float p0 = __builtin_amdgcn_exp2f(s[0]);                             \
        float p1 = __builtin_amdgcn_exp2f(s[1]);                             \
        float p2 = __builtin_amdgcn_exp2f(s[2]);                             \
        float p3 = __builtin_amdgcn_exp2f(s[3]);                             \
        l_acc[st] += (p0 + p1) + (p2 + p3);                                  \
        u32x2 pk = { pkbf(p0, p1), pkbf(p2, p3) };                           \
        s16x4 bP = __builtin_bit_cast(s16x4, pk);                            \
        acc_o[st][0] = __builtin_amdgcn_mfma_f32_16x16x16bf16_1k(            \
            aV0, bP, acc_o[st][0], 0, 0, 0);                                 \
        acc_o[st][1] = __builtin_amdgcn_mfma_f32_16x16x16bf16_1k(            \
            aV1, bP, acc_o[st][1], 0, 0, 0);                                 \
        acc_o[st][2] = __builtin_amdgcn_mfma_f32_16x16x16bf16_1k(            \
            aV2, bP, acc_o[st][2], 0, 0, 0);                                 \
        acc_o[st][3] = __builtin_amdgcn_mfma_f32_16x16x16bf16_1k(            \
            aV3, bP, acc_o[st][3], 0, 0, 0);                                 \
      }                                                                      \
    }                                                                        \
    __builtin_amdgcn_s_setprio(0);                                           \
  }

__global__ __launch_bounds__(256, 3)
void attn_main(const unsigned short* __restrict__ ws, float* __restrict__ out) {
    const int h  = blockIdx.x;      // head pinned to XCD h%8 for L2 locality
    const int qt = blockIdx.y;      // 128-t Q-block
    const int t0 = qt * 128;
    const int tid  = threadIdx.x;
    const int lane = tid & 63;
    const int w    = tid >> 6;      // wave id = t-strip within each 64-t half
    const int ln   = lane & 15, q4 = lane >> 4;

    __shared__ char sbuf[49152];    // 3 x 16KB shared KV staging (tri-buffer)
    char* lbase = sbuf + w * 1024;  // staging: thread covers bytes w*1024+lane*16 (+4K steps)

    // per-lane fragment byte offsets (quarter-local; q*2048 / ci*512 are imms)
    const int aK0o = 2 * frag_off(ln, q4 * 8);
    const int aK1o = 2 * frag_off(ln, 32 + q4 * 8);
    const int aVo  = 32 * ln + 2 * ((q4 ^ ((ln >> 2) & 3)) * 4);

    // Q fragments: rows 16w+ln of each 64-t half (two strips, 4 x 16B loads)
    const unsigned short* qtile = ws + QP_OFF + (size_t)(h * 32 + qt * 2) * 4096;
    bf16x8 bQ[2][2];
    #pragma unroll
    for (int st = 0; st < 2; st++) {
        bQ[st][0] = *(const bf16x8*)(qtile + st * 4096 + frag_off(16 * w + ln, q4 * 8));
        bQ[st][1] = *(const bf16x8*)(qtile + st * 4096 + frag_off(16 * w + ln, 32 + q4 * 8));
    }

    const char* kvb = (const char*)ws + (size_t)(h * 32) * 16384
                      + w * 1024 + lane * 16;
    STAGE(0, 0)                      // tiles 0,1 in flight (8 cps)
    STAGE(1, 1)

    const f32x4 ZF = {0.f, 0.f, 0.f, 0.f};
    f32x4 acc_o[2][4];   // [strip][ci]: O rows c=16ci+q4*4+rr, col t=ln
    #pragma unroll
    for (int st = 0; st < 2; st++)
        #pragma unroll
        for (int ci = 0; ci < 4; ci++) acc_o[st][ci] = ZF;
    float l_acc[2] = {0.f, 0.f};

    // body KT: buf B = KT%3; stages tile KT+2 into SB = (KT+2)%3.
    #pragma unroll 1
    for (int m = 0; m < 10; m++) {   // kt = 0..29
        BODY(3 * m,     0, 2, 1, 0x0F74)   // vmcnt(4)
        BODY(3 * m + 1, 1, 0, 1, 0x0F74)
        BODY(3 * m + 2, 2, 1, 1, 0x0F74)
    }
    BODY(30, 0, 0, 0, 0x0F74)        // no stage; tile 31 still in flight
    BODY(31, 1, 0, 0, 0x0F70)        // vmcnt(0)

    // ---- epilogue: l over q4 groups, direct store (no LDS, no merge) ----
    #pragma unroll
    for (int st = 0; st < 2; st++) {
        float sl = l_acc[st];
        sl += __shfl_xor(sl, 16, 64);
        sl += __shfl_xor(sl, 32, 64);
        const float linv = 1.0f / sl;
        float* ob = out + (size_t)h * D * T + t0 + st * 64 + 16 * w + ln;
        #pragma unroll
        for (int ci = 0; ci < 4; ci++)
            #pragma unroll
            for (int rr = 0; rr < 4; rr++)
                ob[(size_t)(16 * ci + q4 * 4 + rr) * T] = acc_o[st][ci][rr] * linv;
    }
}

// ---------------- fallback (proven): used if ws too small --------------------
__device__ inline bf16x8 frag8(const unsigned short* p, int row, int c0) {
    return *(const bf16x8*)(p + frag_off(row, c0));
}

__global__ __launch_bounds__(256)
void attn_fallback(const float* __restrict__ qkv, float* __restrict__ out) {
    const int h     = blockIdx.y;
    const int t0    = blockIdx.x * 64;
    const int tid   = threadIdx.x;
    const int lane  = tid & 63;
    const int strip = tid >> 6;
    const int ln    = lane & 15;
    const int q4    = lane >> 4;

    __shared__ unsigned short Qs[64 * D];
    __shared__ unsigned short Ks[64 * D];
    __shared__ unsigned short Vs[D * 64];
    __shared__ unsigned short Pss[64 * 64];
    __shared__ float l_lds[64];

    const float* qb = qkv + (size_t)h * 3 * D * T;
    const float* kb = qb + (size_t)D * T;
    const float* vb = qb + (size_t)(2 * D) * T;
    const int s4 = tid & 15;
    const int c0 = (tid >> 4) * 4;
    {
        float fr[4][4];
        #pragma unroll
        for (int r = 0; r < 4; r++)
            *(f32x4*)fr[r] = *(const f32x4*)(qb + (size_t)(c0 + r) * T + t0 + s4 * 4);
        #pragma unroll
        for (int j = 0; j < 4; j++) {
            int trow = s4 * 4 + j;
            u16x4 wv = { f2bf(fr[0][j]), f2bf(fr[1][j]), f2bf(fr[2][j]), f2bf(fr[3][j]) };
            *(u16x4*)(Qs + frag_off(trow, c0) + (c0 & 7)) = wv;
        }
    }
    __syncthreads();
    const int arow = strip * 16 + ln;
    const int kg   = q4 * 8;
    const bf16x8 aq0 = frag8(Qs, arow, kg);
    const bf16x8 aq1 = frag8(Qs, arow, 32 + kg);
    f32x4 acc_o[4];
    #pragma unroll
    for (int m = 0; m < 4; m++) acc_o[m] = (f32x4){0.f, 0.f, 0.f, 0.f};
    float l_acc[4] = {0.f, 0.f, 0.f, 0.f};
    constexpr float S2 = 0.125f * 1.44269504088896340736f;
    for (int kt = 0; kt < NT; kt++) {
        const int s0 = kt * 64;
        float kr[4][4], vr[4][4];
        #pragma unroll
        for (int r = 0; r < 4; r++)
            *(f32x4*)kr[r] = *(const f32x4*)(kb + (size_t)(c0 + r) * T + s0 + s4 * 4);
        #pragma unroll
        for (int r = 0; r < 4; r++)
            *(f32x4*)vr[r] = *(const f32x4*)(vb + (size_t)(c0 + r) * T + s0 + s4 * 4);
        __syncthreads();
        #pragma unroll
        for (int j = 0; j < 4; j++) {
            int srow = s4 * 4 + j;
            u16x4 wk = { f2bf(kr[0][j]), f2bf(kr[1][j]), f2bf(kr[2][j]), f2bf(kr[3][j]) };
            *(u16x4*)(Ks + frag_off(srow, c0) + (c0 & 7)) = wk;
        }
        #pragma unroll
        for (int r = 0; r < 4; r++) {
            int row = c0 + r, cc = s4 * 4;
            u16x4 wv = { f2bf(vr[r][0]), f2bf(vr[r][1]), f2bf(vr[r][2]), f2bf(vr[r][3]) };
            *(u16x4*)(Vs + frag_off(row, cc) + (cc & 7)) = wv;
        }
        __syncthreads();
        f32x4 accs[4];
        #pragma unroll
        for (int ns = 0; ns < 4; ns++) {
            bf16x8 b0 = frag8(Ks, ns * 16 + ln, kg);
            bf16x8 b1 = frag8(Ks, ns * 16 + ln, 32 + kg);
            f32x4 z = {0.f, 0.f, 0.f, 0.f};
            z = __builtin_amdgcn_mfma_f32_16x16x32_bf16(aq0, b0, z, 0, 0, 0);
            z = __builtin_amdgcn_mfma_f32_16x16x32_bf16(aq1, b1, z, 0, 0, 0);
            accs[ns] = z;
        }
        #pragma unroll
        for (int ns = 0; ns < 4; ns++) {
            int scol = ns * 16 + ln;
            #pragma unroll
            for (int r = 0; r < 4; r++) {
                float p = __builtin_amdgcn_exp2f(accs[ns][r] * S2);
                l_acc[r] += p;
                int trow = strip * 16 + q4 * 4 + r;
                int g = ((scol >> 3) ^ ((trow >> 1) & 7));
                Pss[trow * 64 + g * 8 + (scol & 7)] = f2bf(p);
            }
        }
        bf16x8 bp0 = frag8(Pss, arow, kg);
        bf16x8 bp1 = frag8(Pss, arow, 32 + kg);
        #pragma unroll
        for (int ms = 0; ms < 4; ms++) {
            bf16x8 av0 = frag8(Vs, ms * 16 + ln, kg);
            bf16x8 av1 = frag8(Vs, ms * 16 + ln, 32 + kg);
            acc_o[ms] = __builtin_amdgcn_mfma_f32_16x16x32_bf16(av0, bp0, acc_o[ms], 0, 0, 0);
            acc_o[ms] = __builtin_amdgcn_mfma_f32_16x16x32_bf16(av1, bp1, acc_o[ms], 0, 0, 0);
        }
    }
    #pragma unroll
    for (int r = 0; r < 4; r++) {
        float s = l_acc[r];
        s += __shfl_xor(s, 1, 64);
        s += __shfl_xor(s, 2, 64);
        s += __shfl_xor(s, 4, 64);
        s += __shfl_xor(s, 8, 64);
        if (ln == 0) l_lds[strip * 16 + q4 * 4 + r] = s;
    }
    const float linv = 1.0f / l_lds[strip * 16 + ln];
    const int tg = t0 + strip * 16 + ln;
    float* ob = out + (size_t)h * D * T;
    #pragma unroll
    for (int ms = 0; ms < 4; ms++)
        #pragma unroll
        for (int r = 0; r < 4; r++) {
            int c = ms * 16 + q4 * 4 + r;
            ob[(size_t)c * T + tg] = acc_o[ms][r] * linv;
        }
}

} // namespace

extern "C" void kernel_launch(void* const* d_in, const int* in_sizes, int n_in,
                              void* d_out, int out_size, void* d_ws, size_t ws_size,
                              hipStream_t stream) {
    const float* qkv = (const float*)d_in[0];
    float* out = (float*)d_out;
    if (ws_size >= WS_NEED) {
        prepass<<<dim3(32, 64, 3), 256, 0, stream>>>(qkv, (unsigned short*)d_ws);
        attn_main<<<dim3(64, 16), 256, 0, stream>>>((const unsigned short*)d_ws, out);
    } else {
        attn_fallback<<<dim3(32, 64), 256, 0, stream>>>(qkv, out);
    }
}

// Round 9
// 238.863 us; speedup vs baseline: 5.7719x; 1.0547x over previous
//
#include <hip/hip_runtime.h>

namespace {

constexpr int D  = 64;    // channels per head
constexpr int T  = 2048;  // sequence length
constexpr int NT = T / 64;
constexpr float SCL = 0.125f * 1.44269504088896340736f;  // scale^2 * log2(e)

// workspace layout (units: unsigned short):
//  [0, 64*32*8192)             KV tiles: (h*32+kt)*8192
//     K: first 4096 shorts, [s][c] rows of 64, granule-swizzled (16-row quarter = contiguous 2 KB)
//     V: next 4096 shorts, 32-s BLOCKS (j=0,1; 4096 B each): [c][pair-granule],
//        pair-granule (8 shorts) = quarter-lo granule(4 s) ++ quarter-hi granule(4 s),
//        slot = pg ^ ((c>>2)&3). k-order permuted to match P's natural lane layout
//        so PV runs as 16x16x32 with NO cross-lane P fixup.
//  [QP_OFF, ...)               Q tiles: (h*32+qt64)*4096 swizzled [t][c], PRE-SCALED by SCL
constexpr size_t QP_OFF  = (size_t)64 * 32 * 8192;
constexpr size_t WS_NEED = ((size_t)64 * 32 * 8192 + (size_t)64 * 32 * 4096) * 2;  // 50331648 B

typedef __bf16 bf16x8 __attribute__((ext_vector_type(8)));
typedef float  f32x4  __attribute__((ext_vector_type(4)));
typedef unsigned short u16x4 __attribute__((ext_vector_type(4)));
typedef unsigned short u16x8 __attribute__((ext_vector_type(8)));
typedef unsigned int   u32x2 __attribute__((ext_vector_type(2)));
typedef unsigned int   u32x4 __attribute__((ext_vector_type(4)));

__device__ inline unsigned short f2bf(float f) {   // RNE fp32->bf16, finite inputs
    unsigned int u = __builtin_bit_cast(unsigned int, f);
    u += 0x7FFFu + ((u >> 16) & 1u);
    return (unsigned short)(u >> 16);
}

__device__ inline unsigned int pkbf(float a, float b) {
#if __has_builtin(__builtin_amdgcn_cvt_pk_bf16_f32)
    auto r = __builtin_amdgcn_cvt_pk_bf16_f32(a, b);
    static_assert(sizeof(r) == 4, "cvt_pk_bf16 size");
    return __builtin_bit_cast(unsigned int, r);
#else
    return (unsigned int)f2bf(a) | ((unsigned int)f2bf(b) << 16);
#endif
}

// 64-short rows, 16B granules XOR-swizzled by ((row>>1)&7) (K/Q images).
__device__ inline int frag_off(int row, int c0) {
    int g = (c0 >> 3) ^ ((row >> 1) & 7);
    return row * 64 + g * 8;
}

__device__ inline void async_cp16(const void* g, void* l) {
    __builtin_amdgcn_global_load_lds(
        (const __attribute__((address_space(1))) unsigned int*)g,
        (__attribute__((address_space(3))) unsigned int*)l, 16, 0, 0);
}

// ---------------- pre-pass: fp32 -> bf16, swizzled tiles ---------------------
__global__ __launch_bounds__(256)
void prepass(const float* __restrict__ qkv, unsigned short* __restrict__ ws) {
    const int tile = blockIdx.x, h = blockIdx.y, z = blockIdx.z;
    const int tid = threadIdx.x;
    const float* src = qkv + (size_t)h * 3 * D * T + (size_t)z * D * T + tile * 64;
    __shared__ unsigned short L[4096];

    if (z == 2) {  // V: 32-s blocks, k-order-permuted pair-granules (see header)
        unsigned short* dst = ws + (size_t)(h * 32 + tile) * 8192 + 4096;
        const int c = tid >> 2, pg = tid & 3;
        const int slot = pg ^ ((c >> 2) & 3);        // bank-spread slot
        #pragma unroll
        for (int b = 0; b < 2; b++) {
            f32x4 a0 = *(const f32x4*)(src + (size_t)c * T + b * 32 + pg * 4);
            f32x4 a1 = *(const f32x4*)(src + (size_t)c * T + b * 32 + 16 + pg * 4);
            u16x8 wv = { f2bf(a0[0]), f2bf(a0[1]), f2bf(a0[2]), f2bf(a0[3]),
                         f2bf(a1[0]), f2bf(a1[1]), f2bf(a1[2]), f2bf(a1[3]) };
            *(u16x8*)(dst + b * 2048 + c * 32 + slot * 8) = wv;   // 16B stores
        }
    } else {       // Q/K: transpose [c][t] -> swizzled [t][c] via LDS
        const float m = (z == 0) ? SCL : 1.0f;   // fold softmax scale into Q
        const int c0 = (tid >> 4) * 4, s4 = tid & 15;
        float fr[4][4];
        #pragma unroll
        for (int r = 0; r < 4; r++)
            *(f32x4*)fr[r] = *(const f32x4*)(src + (size_t)(c0 + r) * T + s4 * 4);
        #pragma unroll
        for (int j = 0; j < 4; j++) {
            int trow = s4 * 4 + j;
            u16x4 wv = { f2bf(fr[0][j] * m), f2bf(fr[1][j] * m),
                         f2bf(fr[2][j] * m), f2bf(fr[3][j] * m) };
            *(u16x4*)(L + frag_off(trow, c0) + (c0 & 7)) = wv;
        }
        __syncthreads();
        unsigned short* dst = (z == 0)
            ? ws + QP_OFF + (size_t)(h * 32 + tile) * 4096
            : ws + (size_t)(h * 32 + tile) * 8192;
        #pragma unroll
        for (int i = 0; i < 2; i++)
            *(u16x8*)(dst + tid * 16 + i * 8) = *(const u16x8*)(L + tid * 16 + i * 8);
    }
}

// ---------------- main: t-split TQ=128, tri-buffer, K=32 PV ------------------
// R8 skeleton (proven: tri-buffer, single barrier/body, issue-early STAGE,
// setprio) with the PV path converted from 32x 16x16x16_1k (K=16, which
// costs a FULL MFMA slot for HALF the FLOP -- measured: MfmaUtil 43% matches
// the full-slot model exactly) to 16x 16x16x32 over 32-s blocks.
// Legality: MFMA contracts over k; A and B may share ANY k-permutation.
// P's natural lane layout (per quarter: s = q4*4+r) concatenated over two
// quarters gives k = q4*8+e |-> s32 = (e>>2)*16 + q4*4 + (e&3); V is stored
// in the prepass with exactly this k-order (pair-granules), so bPP is a
// pure in-register concat and aV is one ds_read_b128 per (ci, lane).
// V ds_reads: 16x b64 -> 8x b128 per body. MFMA ops/body/wave: 48 -> 32.

#define STAGE(J, SB)                                                         \
  { const char* g = kvb + (size_t)(J) * 16384;                               \
    char* lk = lbase + (SB) * 16384;                                         \
    async_cp16(g,         lk);                                               \
    async_cp16(g + 4096,  lk + 4096);                                        \
    async_cp16(g + 8192,  lk + 8192);                                        \
    async_cp16(g + 12288, lk + 12288); }

#define BODY(KT, B, SB, DO_STAGE, WAITIMM)                                   \
  {                                                                          \
    __builtin_amdgcn_s_waitcnt(WAITIMM);  /* own tile-KT cps landed */       \
    __builtin_amdgcn_s_barrier();         /* ALL waves' tile-KT landed;      \
                                             everyone done reading buf SB */ \
    __builtin_amdgcn_sched_barrier(0);    /* no ds_read hoists above */      \
    if (DO_STAGE) STAGE((KT) + 2, SB)     /* issue-early: hides under MFMA */\
    __builtin_amdgcn_s_setprio(1);                                           \
    _Pragma("unroll")                                                        \
    for (int j = 0; j < 2; j++) {         /* 32-s block = quarters 2j,2j+1 */\
      const char* kq0 = sbuf + (B) * 16384 + (2 * j) * 2048;                 \
      const char* kq1 = kq0 + 2048;                                          \
      const char* vbj = sbuf + (B) * 16384 + 8192 + j * 4096;                \
      bf16x8 aK00 = *(const bf16x8*)(kq0 + aK0o);                            \
      bf16x8 aK01 = *(const bf16x8*)(kq0 + aK1o);                            \
      bf16x8 aK10 = *(const bf16x8*)(kq1 + aK0o);                            \
      bf16x8 aK11 = *(const bf16x8*)(kq1 + aK1o);                            \
      bf16x8 aV0 = *(const bf16x8*)(vbj + aVo);                              \
      bf16x8 aV1 = *(const bf16x8*)(vbj + aVo + 1024);                       \
      bf16x8 aV2 = *(const bf16x8*)(vbj + aVo + 2048);                       \
      bf16x8 aV3 = *(const bf16x8*)(vbj + aVo + 3072);                       \
      _Pragma("unroll")                                                      \
      for (int st = 0; st < 2; st++) {                                       \
        f32x4 s0 = __builtin_amdgcn_mfma_f32_16x16x32_bf16(                  \
            aK00, bQ[st][0], ZF, 0, 0, 0);                                   \
        s0 = __builtin_amdgcn_mfma_f32_16x16x32_bf16(                        \
            aK01, bQ[st][1], s0, 0, 0, 0);                                   \
        f32x4 s1 = __builtin_amdgcn_mfma_f32_16x16x32_bf16(                  \
            aK10, bQ[st][0], ZF, 0, 0, 0);                                   \
        s1 = __builtin_amdgcn_mfma_f32_16x16x32_bf16(                        \
            aK11, bQ[st][1], s1, 0, 0, 0);                                   \
        float p0 = __builtin_amdgcn_exp2f(s0[0]);                            \
        float p1 = __builtin_amdgcn_exp2f(s0[1]);                            \
        float p2 = __builtin_amdgcn_exp2f(s0[2]);                            \
        float p3 = __builtin_amdgcn_exp2f(s0[3]);                            \
        float q0 = __builtin_amdgcn_exp2f(s1[0]);                            \
        float q1 = __builtin_amdgcn_exp2f(s1[1]);                            \
        float q2 = __builtin_amdgcn_exp2f(s1[2]);                            \
        float q3 = __builtin_amdgcn_exp2f(s1[3]);                            \
        l_acc[st] += ((p0 + p1) + (p2 + p3)) + ((q0 + q1) + (q2 + q3));      \
        u32x4 pk = { pkbf(p0, p1), pkbf(p2, p3),                             \
                     pkbf(q0, q1), pkbf(q2, q3) };                           \
        bf16x8 bPP = __builtin_bit_cast(bf16x8, pk);                         \
        acc_o[st][0] = __builtin_amdgcn_mfma_f32_16x16x32_bf16(              \
            aV0, bPP, acc_o[st][0], 0, 0, 0);                                \
        acc_o[st][1] = __builtin_amdgcn_mfma_f32_16x16x32_bf16(              \
            aV1, bPP, acc_o[st][1], 0, 0, 0);                                \
        acc_o[st][2] = __builtin_amdgcn_mfma_f32_16x16x32_bf16(              \
            aV2, bPP, acc_o[st][2], 0, 0, 0);                                \
        acc_o[st][3] = __builtin_amdgcn_mfma_f32_16x16x32_bf16(              \
            aV3, bPP, acc_o[st][3], 0, 0, 0);                                \
      }                                                                      \
    }                                                                        \
    __builtin_amdgcn_s_setprio(0);                                           \
  }

__global__ __launch_bounds__(256, 3)
void attn_main(const unsigned short* __restrict__ ws, float* __restrict__ out) {
    const int h  = blockIdx.x;      // head pinned to XCD h%8 for L2 locality
    const int qt = blockIdx.y;      // 128-t Q-block
    const int t0 = qt * 128;
    const int tid  = threadIdx.x;
    const int lane = tid & 63;
    const int w    = tid >> 6;      // wave id = t-strip within each 64-t half
    const int ln   = lane & 15, q4 = lane >> 4;

    __shared__ char sbuf[49152];    // 3 x 16KB shared KV staging (tri-buffer)
    char* lbase = sbuf + w * 1024;  // staging: thread covers bytes w*1024+lane*16 (+4K steps)

    // per-lane fragment byte offsets
    const int aK0o = 2 * frag_off(ln, q4 * 8);
    const int aK1o = 2 * frag_off(ln, 32 + q4 * 8);
    // V (A-operand, K=32): row c = ci*16+ln (64 B/row), slot = q4^((ln>>2)&3).
    // Content at that slot is pair pg = q4 (write swizzle cancels): k-order
    // k=q4*8+e |-> s32=(e>>2)*16+q4*4+(e&3), matching bPP. +1024 B per ci.
    const int aVo  = 64 * ln + ((q4 ^ ((ln >> 2) & 3)) * 16);

    // Q fragments: rows 16w+ln of each 64-t half (two strips, 4 x 16B loads)
    const unsigned short* qtile = ws + QP_OFF + (size_t)(h * 32 + qt * 2) * 4096;
    bf16x8 bQ[2][2];
    #pragma unroll
    for (int st = 0; st < 2; st++) {
        bQ[st][0] = *(const bf16x8*)(qtile + st * 4096 + frag_off(16 * w + ln, q4 * 8));
        bQ[st][1] = *(const bf16x8*)(qtile + st * 4096 + frag_off(16 * w + ln, 32 + q4 * 8));
    }

    const char* kvb = (const char*)ws + (size_t)(h * 32) * 16384
                      + w * 1024 + lane * 16;
    STAGE(0, 0)                      // tiles 0,1 in flight (8 cps)
    STAGE(1, 1)

    const f32x4 ZF = {0.f, 0.f, 0.f, 0.f};
    f32x4 acc_o[2][4];   // [strip][ci]: O rows c=16ci+q4*4+rr, col t=ln
    #pragma unroll
    for (int st = 0; st < 2; st++)
        #pragma unroll
        for (int ci = 0; ci < 4; ci++) acc_o[st][ci] = ZF;
    float l_acc[2] = {0.f, 0.f};

    // body KT: buf B = KT%3; stages tile KT+2 into SB = (KT+2)%3.
    #pragma unroll 1
    for (int m = 0; m < 10; m++) {   // kt = 0..29
        BODY(3 * m,     0, 2, 1, 0x0F74)   // vmcnt(4)
        BODY(3 * m + 1, 1, 0, 1, 0x0F74)
        BODY(3 * m + 2, 2, 1, 1, 0x0F74)
    }
    BODY(30, 0, 0, 0, 0x0F74)        // no stage; tile 31 still in flight
    BODY(31, 1, 0, 0, 0x0F70)        // vmcnt(0)

    // ---- epilogue: l over q4 groups, direct store (no LDS, no merge) ----
    #pragma unroll
    for (int st = 0; st < 2; st++) {
        float sl = l_acc[st];
        sl += __shfl_xor(sl, 16, 64);
        sl += __shfl_xor(sl, 32, 64);
        const float linv = 1.0f / sl;
        float* ob = out + (size_t)h * D * T + t0 + st * 64 + 16 * w + ln;
        #pragma unroll
        for (int ci = 0; ci < 4; ci++)
            #pragma unroll
            for (int rr = 0; rr < 4; rr++)
                ob[(size_t)(16 * ci + q4 * 4 + rr) * T] = acc_o[st][ci][rr] * linv;
    }
}

// ---------------- fallback (proven): used if ws too small --------------------
__device__ inline bf16x8 frag8(const unsigned short* p, int row, int c0) {
    return *(const bf16x8*)(p + frag_off(row, c0));
}

__global__ __launch_bounds__(256)
void attn_fallback(const float* __restrict__ qkv, float* __restrict__ out) {
    const int h     = blockIdx.y;
    const int t0    = blockIdx.x * 64;
    const int tid   = threadIdx.x;
    const int lane  = tid & 63;
    const int strip = tid >> 6;
    const int ln    = lane & 15;
    const int q4    = lane >> 4;

    __shared__ unsigned short Qs[64 * D];
    __shared__ unsigned short Ks[64 * D];
    __shared__ unsigned short Vs[D * 64];
    __shared__ unsigned short Pss[64 * 64];
    __shared__ float l_lds[64];

    const float* qb = qkv + (size_t)h * 3 * D * T;
    const float* kb = qb + (size_t)D * T;
    const float* vb = qb + (size_t)(2 * D) * T;
    const int s4 = tid & 15;
    const int c0 = (tid >> 4) * 4;
    {
        float fr[4][4];
        #pragma unroll
        for (int r = 0; r < 4; r++)
            *(f32x4*)fr[r] = *(const f32x4*)(qb + (size_t)(c0 + r) * T + t0 + s4 * 4);
        #pragma unroll
        for (int j = 0; j < 4; j++) {
            int trow = s4 * 4 + j;
            u16x4 wv = { f2bf(fr[0][j]), f2bf(fr[1][j]), f2bf(fr[2][j]), f2bf(fr[3][j]) };
            *(u16x4*)(Qs + frag_off(trow, c0) + (c0 & 7)) = wv;
        }
    }
    __syncthreads();
    const int arow = strip * 16 + ln;
    const int kg   = q4 * 8;
    const bf16x8 aq0 = frag8(Qs, arow, kg);
    const bf16x8 aq1 = frag8(Qs, arow, 32 + kg);
    f32x4 acc_o[4];
    #pragma unroll
    for (int m = 0; m < 4; m++) acc_o[m] = (f32x4){0.f, 0.f, 0.f, 0.f};
    float l_acc[4] = {0.f, 0.f, 0.f, 0.f};
    constexpr float S2 = 0.125f * 1.44269504088896340736f;
    for (int kt = 0; kt < NT; kt++) {
        const int s0 = kt * 64;
        float kr[4][4], vr[4][4];
        #pragma unroll
        for (int r = 0; r < 4; r++)
            *(f32x4*)kr[r] = *(const f32x4*)(kb + (size_t)(c0 + r) * T + s0 + s4 * 4);
        #pragma unroll
        for (int r = 0; r < 4; r++)
            *(f32x4*)vr[r] = *(const f32x4*)(vb + (size_t)(c0 + r) * T + s0 + s4 * 4);
        __syncthreads();
        #pragma unroll
        for (int j = 0; j < 4; j++) {
            int srow = s4 * 4 + j;
            u16x4 wk = { f2bf(kr[0][j]), f2bf(kr[1][j]), f2bf(kr[2][j]), f2bf(kr[3][j]) };
            *(u16x4*)(Ks + frag_off(srow, c0) + (c0 & 7)) = wk;
        }
        #pragma unroll
        for (int r = 0; r < 4; r++) {
            int row = c0 + r, cc = s4 * 4;
            u16x4 wv = { f2bf(vr[r][0]), f2bf(vr[r][1]), f2bf(vr[r][2]), f2bf(vr[r][3]) };
            *(u16x4*)(Vs + frag_off(row, cc) + (cc & 7)) = wv;
        }
        __syncthreads();
        f32x4 accs[4];
        #pragma unroll
        for (int ns = 0; ns < 4; ns++) {
            bf16x8 b0 = frag8(Ks, ns * 16 + ln, kg);
            bf16x8 b1 = frag8(Ks, ns * 16 + ln, 32 + kg);
            f32x4 z = {0.f, 0.f, 0.f, 0.f};
            z = __builtin_amdgcn_mfma_f32_16x16x32_bf16(aq0, b0, z, 0, 0, 0);
            z = __builtin_amdgcn_mfma_f32_16x16x32_bf16(aq1, b1, z, 0, 0, 0);
            accs[ns] = z;
        }
        #pragma unroll
        for (int ns = 0; ns < 4; ns++) {
            int scol = ns * 16 + ln;
            #pragma unroll
            for (int r = 0; r < 4; r++) {
                float p = __builtin_amdgcn_exp2f(accs[ns][r] * S2);
                l_acc[r] += p;
                int trow = strip * 16 + q4 * 4 + r;
                int g = ((scol >> 3) ^ ((trow >> 1) & 7));
                Pss[trow * 64 + g * 8 + (scol & 7)] = f2bf(p);
            }
        }
        bf16x8 bp0 = frag8(Pss, arow, kg);
        bf16x8 bp1 = frag8(Pss, arow, 32 + kg);
        #pragma unroll
        for (int ms = 0; ms < 4; ms++) {
            bf16x8 av0 = frag8(Vs, ms * 16 + ln, kg);
            bf16x8 av1 = frag8(Vs, ms * 16 + ln, 32 + kg);
            acc_o[ms] = __builtin_amdgcn_mfma_f32_16x16x32_bf16(av0, bp0, acc_o[ms], 0, 0, 0);
            acc_o[ms] = __builtin_amdgcn_mfma_f32_16x16x32_bf16(av1, bp1, acc_o[ms], 0, 0, 0);
        }
    }
    #pragma unroll
    for (int r = 0; r < 4; r++) {
        float s = l_acc[r];
        s += __shfl_xor(s, 1, 64);
        s += __shfl_xor(s, 2, 64);
        s += __shfl_xor(s, 4, 64);
        s += __shfl_xor(s, 8, 64);
        if (ln == 0) l_lds[strip * 16 + q4 * 4 + r] = s;
    }
    const float linv = 1.0f / l_lds[strip * 16 + ln];
    const int tg = t0 + strip * 16 + ln;
    float* ob = out + (size_t)h * D * T;
    #pragma unroll
    for (int ms = 0; ms < 4; ms++)
        #pragma unroll
        for (int r = 0; r < 4; r++) {
            int c = ms * 16 + q4 * 4 + r;
            ob[(size_t)c * T + tg] = acc_o[ms][r] * linv;
        }
}

} // namespace

extern "C" void kernel_launch(void* const* d_in, const int* in_sizes, int n_in,
                              void* d_out, int out_size, void* d_ws, size_t ws_size,
                              hipStream_t stream) {
    const float* qkv = (const float*)d_in[0];
    float* out = (float*)d_out;
    if (ws_size >= WS_NEED) {
        prepass<<<dim3(32, 64, 3), 256, 0, stream>>>(qkv, (unsigned short*)d_ws);
        attn_main<<<dim3(64, 16), 256, 0, stream>>>((const unsigned short*)d_ws, out);
    } else {
        attn_fallback<<<dim3(32, 64), 256, 0, stream>>>(qkv, out);
    }
}